// Round 1
// baseline (396.287 us; speedup 1.0000x reference)
//
#include <hip/hip_runtime.h>
#include <hip/hip_bf16.h>
#include <stdint.h>

typedef __bf16 bf16_t;
typedef bf16_t bf16x8 __attribute__((ext_vector_type(8)));
typedef float f32x4 __attribute__((ext_vector_type(4)));

#define D_IN 64
#define D_OUT 64
#define BM 128
#define NTHREADS 512

// XOR-swizzled byte offset into a [rows][64] bf16 LDS tile (row stride 128 B).
// Spreads the stride-128B column reads across 8 distinct 16B slots (2-way max,
// which is free per G4/m136). Preserves 16B alignment for b128 ops.
__device__ __forceinline__ uint32_t swz(int row, int col) {
    return (uint32_t)((row * 128 + col * 2) ^ ((row & 7) << 4));
}

__global__ __launch_bounds__(NTHREADS, 1) void subm_conv_mfma(
    const float* __restrict__ feats,
    const int* __restrict__ indices,
    const float* __restrict__ weight,
    float* __restrict__ out,
    int n_vox, int k3)
{
    __shared__ bf16_t As[BM * 64];   // 16 KB, swizzled
    __shared__ bf16_t Bs[64 * 64];   // 8 KB,  swizzled; Bs[dp][d] = W[k][d][dp]

    const int tid  = threadIdx.x;
    const int lane = tid & 63;
    const int wv   = tid >> 6;          // wave 0..7
    const int wr   = (wv >> 1) * 32;    // wave row base within tile (0,32,64,96)
    const int wc   = (wv & 1) * 32;     // wave col base (0,32)
    const int l15  = lane & 15;
    const int l4   = lane >> 4;
    const int n0   = blockIdx.x * BM;

    // A-staging role: 4 threads per row, 16 fp32 each
    const int ar = tid >> 2;            // row 0..127
    const int ac = (tid & 3) * 16;      // col start 0,16,32,48
    // B-staging role: 1 thread per (dp, 8-d-group)
    const int bdp = tid & 63;
    const int bd0 = (tid >> 6) * 8;

    f32x4 acc[2][2];
    #pragma unroll
    for (int i = 0; i < 2; ++i)
        #pragma unroll
        for (int j = 0; j < 2; ++j)
            acc[i][j] = (f32x4){0.f, 0.f, 0.f, 0.f};

    for (int k = 0; k < k3; ++k) {
        __syncthreads();   // previous iteration's LDS reads complete

        // ---- stage A: gather feats rows, fp32 -> bf16 ----
        {
            const int n = n0 + ar;
            int idx = (n < n_vox) ? indices[k * n_vox + n] : -1;
            bf16x8 v0 = {}, v1 = {};
            if (idx >= 0) {
                const float* src = feats + idx * D_IN + ac;
                f32x4 f0 = *(const f32x4*)(src + 0);
                f32x4 f1 = *(const f32x4*)(src + 4);
                f32x4 f2 = *(const f32x4*)(src + 8);
                f32x4 f3 = *(const f32x4*)(src + 12);
                #pragma unroll
                for (int i = 0; i < 4; ++i) {
                    v0[i]     = (bf16_t)f0[i];
                    v0[i + 4] = (bf16_t)f1[i];
                    v1[i]     = (bf16_t)f2[i];
                    v1[i + 4] = (bf16_t)f3[i];
                }
            }
            *(bf16x8*)((char*)As + swz(ar, ac))     = v0;
            *(bf16x8*)((char*)As + swz(ar, ac + 8)) = v1;
        }

        // ---- stage B transposed: Bs[dp][d] = W[k][d][dp] ----
        {
            const float* wsrc = weight + k * (D_IN * D_OUT) + bd0 * D_OUT + bdp;
            bf16x8 v;
            #pragma unroll
            for (int i = 0; i < 8; ++i)
                v[i] = (bf16_t)wsrc[i * D_OUT];
            *(bf16x8*)((char*)Bs + swz(bdp, bd0)) = v;
        }

        __syncthreads();

        // ---- MFMA: 2 K-steps of 32, 2x2 fragments per wave ----
        #pragma unroll
        for (int ks = 0; ks < 2; ++ks) {
            const int kc = ks * 32 + l4 * 8;
            bf16x8 a0 = *(const bf16x8*)((char*)As + swz(wr + l15,      kc));
            bf16x8 a1 = *(const bf16x8*)((char*)As + swz(wr + 16 + l15, kc));
            bf16x8 b0 = *(const bf16x8*)((char*)Bs + swz(wc + l15,      kc));
            bf16x8 b1 = *(const bf16x8*)((char*)Bs + swz(wc + 16 + l15, kc));
            acc[0][0] = __builtin_amdgcn_mfma_f32_16x16x32_bf16(a0, b0, acc[0][0], 0, 0, 0);
            acc[0][1] = __builtin_amdgcn_mfma_f32_16x16x32_bf16(a0, b1, acc[0][1], 0, 0, 0);
            acc[1][0] = __builtin_amdgcn_mfma_f32_16x16x32_bf16(a1, b0, acc[1][0], 0, 0, 0);
            acc[1][1] = __builtin_amdgcn_mfma_f32_16x16x32_bf16(a1, b1, acc[1][1], 0, 0, 0);
        }
    }

    // ---- epilogue: C/D layout col = lane&15, row = (lane>>4)*4 + reg ----
    #pragma unroll
    for (int mi = 0; mi < 2; ++mi)
        #pragma unroll
        for (int ni = 0; ni < 2; ++ni)
            #pragma unroll
            for (int j = 0; j < 4; ++j) {
                const int row = n0 + wr + mi * 16 + l4 * 4 + j;
                const int col = wc + ni * 16 + l15;
                if (row < n_vox)
                    out[row * D_OUT + col] = acc[mi][ni][j];
            }
}

extern "C" void kernel_launch(void* const* d_in, const int* in_sizes, int n_in,
                              void* d_out, int out_size, void* d_ws, size_t ws_size,
                              hipStream_t stream) {
    const float* feats   = (const float*)d_in[0];
    const int*   indices = (const int*)d_in[1];     // harness normalizes ints to int32
    const float* weight  = (const float*)d_in[2];
    float* out = (float*)d_out;

    const int n_vox = in_sizes[0] / D_IN;
    const int k3    = in_sizes[2] / (D_IN * D_OUT);
    const int grid  = (n_vox + BM - 1) / BM;

    subm_conv_mfma<<<grid, NTHREADS, 0, stream>>>(feats, indices, weight, out, n_vox, k3);
}

// Round 2
// 244.968 us; speedup vs baseline: 1.6177x; 1.6177x over previous
//
#include <hip/hip_runtime.h>
#include <hip/hip_bf16.h>
#include <stdint.h>

typedef __bf16 bf16_t;
typedef bf16_t bf16x8 __attribute__((ext_vector_type(8)));
typedef float f32x4 __attribute__((ext_vector_type(4)));

#define D_IN 64
#define D_OUT 64
#define BM 128
#define NTHREADS 512

// Async global->LDS, 16 B per lane. LDS dest must be wave-uniform base;
// HW writes lane i at base + i*16.
#define GLOAD_LDS16(gsrc, ldst)                                                     \
    __builtin_amdgcn_global_load_lds(                                               \
        (const __attribute__((address_space(1))) uint32_t*)(gsrc),                  \
        (__attribute__((address_space(3))) uint32_t*)(ldst), 16, 0, 0)

// XOR-swizzled byte offset into a [rows][64] bf16 tile (row stride 128 B).
// col in bf16 elements. Spreads stride-128B column reads across 8 16B slots.
__device__ __forceinline__ uint32_t swz(int row, int col) {
    return (uint32_t)((row * 128 + col * 2) ^ ((row & 7) << 4));
}

// ---------------- pre-pass 1: feats fp32 -> bf16 (+ zero row at index N) ----
__global__ void convert_feats(const float* __restrict__ feats,
                              bf16_t* __restrict__ fb,
                              int n_elems /* N*64 */, int total8 /* (N+1)*8 */) {
    int g = blockIdx.x * blockDim.x + threadIdx.x;
    for (; g < total8; g += gridDim.x * blockDim.x) {
        const int e = g * 8;
        bf16x8 v = {};
        if (e < n_elems) {
            f32x4 a = *(const f32x4*)(feats + e);
            f32x4 b = *(const f32x4*)(feats + e + 4);
            #pragma unroll
            for (int i = 0; i < 4; ++i) {
                v[i]     = (bf16_t)a[i];
                v[i + 4] = (bf16_t)b[i];
            }
        }
        *(bf16x8*)(fb + e) = v;
    }
}

// ---------------- pre-pass 2: weight -> transposed + inverse-swizzled bf16 --
// wtb[k] is an 8 KB image of the Bs LDS tile as written LINEARLY by
// global_load_lds; linear slot (dp = t>>3, c' = t&7) must hold logical chunk
// c = c' ^ (dp&7) of Wt[dp][*] where Wt[dp][d] = W[k][d][dp].
__global__ void convert_weight(const float* __restrict__ w,
                               bf16_t* __restrict__ wtb, int k3) {
    const int k = blockIdx.x;
    const int tid = threadIdx.x;              // 512
    const int dp = tid >> 3;
    const int cp = tid & 7;
    const int d0 = (cp ^ (dp & 7)) * 8;
    const float* src = w + (size_t)k * (D_IN * D_OUT) + (size_t)d0 * D_OUT + dp;
    bf16x8 v;
    #pragma unroll
    for (int j = 0; j < 8; ++j) v[j] = (bf16_t)src[j * D_OUT];
    *(bf16x8*)((char*)wtb + (size_t)k * 8192 + tid * 16) = v;
}

// ---------------- main kernel ----------------------------------------------
__global__ __launch_bounds__(NTHREADS, 1) void subm_conv_mfma2(
    const bf16_t* __restrict__ fb,      // (N+1) rows x 128 B, row N = zeros
    const int* __restrict__ indices,
    const bf16_t* __restrict__ wtb,     // k3 x 8192 B, pre-swizzled
    float* __restrict__ out,
    int n_vox, int k3)
{
    __shared__ __align__(16) bf16_t As[2][BM * 64];   // 2 x 16 KB
    __shared__ __align__(16) bf16_t Bs[2][64 * 64];   // 2 x  8 KB

    const int tid  = threadIdx.x;
    const int lane = tid & 63;
    const int wv   = tid >> 6;
    const int l15  = lane & 15;
    const int l4   = lane >> 4;
    const int wr   = (wv >> 1) * 32;
    const int wc   = (wv & 1) * 32;
    const int n0   = blockIdx.x * BM;

    // A-staging geometry: wave wv owns tile rows [wv*16, wv*16+16), two
    // issues of 8 rows x 8 chunks (64 lanes each).
    const int rA0 = wv * 16 + (lane >> 3);
    const int rA1 = rA0 + 8;
    const int cp  = lane & 7;
    const uint32_t so0 = (uint32_t)((cp ^ (rA0 & 7)) * 16);  // pre-swizzled src chunk
    const uint32_t so1 = (uint32_t)((cp ^ (rA1 & 7)) * 16);

    int ia0 = -1, ia1 = -1;   // idx prefetch registers (for tile k+1 ahead)

    #define LOADIDX(kk) do {                                                   \
        const int* ip = indices + (size_t)(kk) * n_vox + n0;                   \
        ia0 = (n0 + rA0 < n_vox) ? ip[rA0] : -1;                               \
        ia1 = (n0 + rA1 < n_vox) ? ip[rA1] : -1;                               \
    } while (0)

    #define STAGE(buf, kk) do {                                                \
        /* B: one 16B load per thread, fully linear both sides */              \
        GLOAD_LDS16((const char*)wtb + (size_t)(kk) * 8192 + tid * 16,         \
                    (char*)&Bs[buf][0] + wv * 1024);                           \
        /* A: gather, 2 issues of 8 rows per wave */                           \
        const size_t r0 = (size_t)((ia0 >= 0 && ia0 < n_vox) ? ia0 : n_vox);   \
        const size_t r1 = (size_t)((ia1 >= 0 && ia1 < n_vox) ? ia1 : n_vox);   \
        GLOAD_LDS16((const char*)fb + r0 * 128 + so0,                          \
                    (char*)&As[buf][0] + wv * 2048);                           \
        GLOAD_LDS16((const char*)fb + r1 * 128 + so1,                          \
                    (char*)&As[buf][0] + wv * 2048 + 1024);                    \
    } while (0)

    f32x4 acc[2][2];
    #pragma unroll
    for (int i = 0; i < 2; ++i)
        #pragma unroll
        for (int j = 0; j < 2; ++j)
            acc[i][j] = (f32x4){0.f, 0.f, 0.f, 0.f};

    LOADIDX(0);
    STAGE(0, 0);
    if (k3 > 1) LOADIDX(1);

    for (int k = 0; k < k3; ++k) {
        // Drains vmcnt(0): stage(k) complete; all reads of buf[(k+1)&1]
        // (done in iter k-1 before its barrier) are finished.
        __syncthreads();

        if (k + 1 < k3) STAGE((k + 1) & 1, k + 1);   // in flight across MFMA
        if (k + 2 < k3) LOADIDX(k + 2);

        const char* ab = (const char*)&As[k & 1][0];
        const char* bb = (const char*)&Bs[k & 1][0];
        #pragma unroll
        for (int ks = 0; ks < 2; ++ks) {
            const int kc = ks * 32 + l4 * 8;
            bf16x8 a0 = *(const bf16x8*)(ab + swz(wr + l15,      kc));
            bf16x8 a1 = *(const bf16x8*)(ab + swz(wr + 16 + l15, kc));
            bf16x8 b0 = *(const bf16x8*)(bb + swz(wc + l15,      kc));
            bf16x8 b1 = *(const bf16x8*)(bb + swz(wc + 16 + l15, kc));
            acc[0][0] = __builtin_amdgcn_mfma_f32_16x16x32_bf16(a0, b0, acc[0][0], 0, 0, 0);
            acc[0][1] = __builtin_amdgcn_mfma_f32_16x16x32_bf16(a0, b1, acc[0][1], 0, 0, 0);
            acc[1][0] = __builtin_amdgcn_mfma_f32_16x16x32_bf16(a1, b0, acc[1][0], 0, 0, 0);
            acc[1][1] = __builtin_amdgcn_mfma_f32_16x16x32_bf16(a1, b1, acc[1][1], 0, 0, 0);
        }
    }

    // C/D layout: col = lane&15, row = (lane>>4)*4 + reg
    #pragma unroll
    for (int mi = 0; mi < 2; ++mi)
        #pragma unroll
        for (int ni = 0; ni < 2; ++ni)
            #pragma unroll
            for (int j = 0; j < 4; ++j) {
                const int row = n0 + wr + mi * 16 + l4 * 4 + j;
                const int col = wc + ni * 16 + l15;
                if (row < n_vox)
                    out[(size_t)row * D_OUT + col] = acc[mi][ni][j];
            }
    #undef LOADIDX
    #undef STAGE
}

// ---------------- fallback (round-1 kernel, used if ws too small) ----------
__global__ __launch_bounds__(NTHREADS, 1) void subm_conv_mfma_v1(
    const float* __restrict__ feats,
    const int* __restrict__ indices,
    const float* __restrict__ weight,
    float* __restrict__ out,
    int n_vox, int k3)
{
    __shared__ bf16_t As[BM * 64];
    __shared__ bf16_t Bs[64 * 64];

    const int tid  = threadIdx.x;
    const int lane = tid & 63;
    const int wv   = tid >> 6;
    const int wr   = (wv >> 1) * 32;
    const int wc   = (wv & 1) * 32;
    const int l15  = lane & 15;
    const int l4   = lane >> 4;
    const int n0   = blockIdx.x * BM;

    const int ar = tid >> 2;
    const int ac = (tid & 3) * 16;
    const int bdp = tid & 63;
    const int bd0 = (tid >> 6) * 8;

    f32x4 acc[2][2];
    #pragma unroll
    for (int i = 0; i < 2; ++i)
        #pragma unroll
        for (int j = 0; j < 2; ++j)
            acc[i][j] = (f32x4){0.f, 0.f, 0.f, 0.f};

    for (int k = 0; k < k3; ++k) {
        __syncthreads();
        {
            const int n = n0 + ar;
            int idx = (n < n_vox) ? indices[(size_t)k * n_vox + n] : -1;
            bf16x8 v0 = {}, v1 = {};
            if (idx >= 0) {
                const float* src = feats + (size_t)idx * D_IN + ac;
                f32x4 f0 = *(const f32x4*)(src + 0);
                f32x4 f1 = *(const f32x4*)(src + 4);
                f32x4 f2 = *(const f32x4*)(src + 8);
                f32x4 f3 = *(const f32x4*)(src + 12);
                #pragma unroll
                for (int i = 0; i < 4; ++i) {
                    v0[i]     = (bf16_t)f0[i];
                    v0[i + 4] = (bf16_t)f1[i];
                    v1[i]     = (bf16_t)f2[i];
                    v1[i + 4] = (bf16_t)f3[i];
                }
            }
            *(bf16x8*)((char*)As + swz(ar, ac))     = v0;
            *(bf16x8*)((char*)As + swz(ar, ac + 8)) = v1;
        }
        {
            const float* wsrc = weight + (size_t)k * (D_IN * D_OUT) + (size_t)bd0 * D_OUT + bdp;
            bf16x8 v;
            #pragma unroll
            for (int i = 0; i < 8; ++i) v[i] = (bf16_t)wsrc[i * D_OUT];
            *(bf16x8*)((char*)Bs + swz(bdp, bd0)) = v;
        }
        __syncthreads();
        #pragma unroll
        for (int ks = 0; ks < 2; ++ks) {
            const int kc = ks * 32 + l4 * 8;
            bf16x8 a0 = *(const bf16x8*)((char*)As + swz(wr + l15,      kc));
            bf16x8 a1 = *(const bf16x8*)((char*)As + swz(wr + 16 + l15, kc));
            bf16x8 b0 = *(const bf16x8*)((char*)Bs + swz(wc + l15,      kc));
            bf16x8 b1 = *(const bf16x8*)((char*)Bs + swz(wc + 16 + l15, kc));
            acc[0][0] = __builtin_amdgcn_mfma_f32_16x16x32_bf16(a0, b0, acc[0][0], 0, 0, 0);
            acc[0][1] = __builtin_amdgcn_mfma_f32_16x16x32_bf16(a0, b1, acc[0][1], 0, 0, 0);
            acc[1][0] = __builtin_amdgcn_mfma_f32_16x16x32_bf16(a1, b0, acc[1][0], 0, 0, 0);
            acc[1][1] = __builtin_amdgcn_mfma_f32_16x16x32_bf16(a1, b1, acc[1][1], 0, 0, 0);
        }
    }

    #pragma unroll
    for (int mi = 0; mi < 2; ++mi)
        #pragma unroll
        for (int ni = 0; ni < 2; ++ni)
            #pragma unroll
            for (int j = 0; j < 4; ++j) {
                const int row = n0 + wr + mi * 16 + l4 * 4 + j;
                const int col = wc + ni * 16 + l15;
                if (row < n_vox)
                    out[(size_t)row * D_OUT + col] = acc[mi][ni][j];
            }
}

extern "C" void kernel_launch(void* const* d_in, const int* in_sizes, int n_in,
                              void* d_out, int out_size, void* d_ws, size_t ws_size,
                              hipStream_t stream) {
    const float* feats   = (const float*)d_in[0];
    const int*   indices = (const int*)d_in[1];
    const float* weight  = (const float*)d_in[2];
    float* out = (float*)d_out;

    const int n_vox = in_sizes[0] / D_IN;
    const int k3    = in_sizes[2] / (D_IN * D_OUT);
    const int grid  = (n_vox + BM - 1) / BM;

    const size_t fb_bytes  = (size_t)(n_vox + 1) * D_IN * sizeof(bf16_t);
    const size_t fb_off    = 0;
    const size_t wtb_off   = (fb_bytes + 255) & ~(size_t)255;
    const size_t wtb_bytes = (size_t)k3 * 64 * 64 * sizeof(bf16_t);
    const size_t need      = wtb_off + wtb_bytes;

    if (ws_size >= need) {
        bf16_t* fb  = (bf16_t*)((char*)d_ws + fb_off);
        bf16_t* wtb = (bf16_t*)((char*)d_ws + wtb_off);

        const int n_elems = n_vox * D_IN;
        const int total8  = (n_vox + 1) * (D_IN / 8);
        int cblocks = (total8 + 255) / 256;
        if (cblocks > 2048) cblocks = 2048;
        convert_feats<<<cblocks, 256, 0, stream>>>(feats, fb, n_elems, total8);
        convert_weight<<<k3, 512, 0, stream>>>(weight, wtb, k3);
        subm_conv_mfma2<<<grid, NTHREADS, 0, stream>>>(fb, indices, wtb, out, n_vox, k3);
    } else {
        subm_conv_mfma_v1<<<grid, NTHREADS, 0, stream>>>(feats, indices, weight, out, n_vox, k3);
    }
}